// Round 9
// baseline (167.741 us; speedup 1.0000x reference)
//
#include <hip/hip_runtime.h>

// Problem constants (match reference: B=16, S=4096, D=128)
#define BB   16
#define SS   4096
#define DD   128
#define NCH  512            // chunks per batch
#define TT   (SS / NCH)     // 8 steps per chunk
#define WPB  4              // waves (=chunks) per block
#define NTHR 256
#define NWAVE (BB * NCH)    // 8192 chunks

#define LN_EPS  1e-5f
#define REC_EPS 1e-8f

__device__ __forceinline__ float fast_rcp(float x) { return __builtin_amdgcn_rcpf(x); }
__device__ __forceinline__ float sigm(float x) { return fast_rcp(1.0f + __expf(-x)); }

// DPP shifted copy with 0-fill (bound_ctrl=1). CTRL is a compile-time const.
template<int CTRL>
__device__ __forceinline__ float dpp_mov0(float x) {
    return __int_as_float(
        __builtin_amdgcn_update_dpp(0, __float_as_int(x), CTRL, 0xF, 0xF, true));
}

// Full 64-lane wave sum of two values, VALU-only (HW-verified in prior rounds).
__device__ __forceinline__ void wave_red2(float& a, float& b) {
    a += dpp_mov0<0x111>(a); b += dpp_mov0<0x111>(b);   // row_shr:1
    a += dpp_mov0<0x112>(a); b += dpp_mov0<0x112>(b);   // row_shr:2
    a += dpp_mov0<0x114>(a); b += dpp_mov0<0x114>(b);   // row_shr:4
    a += dpp_mov0<0x118>(a); b += dpp_mov0<0x118>(b);   // row_shr:8
    a += dpp_mov0<0x142>(a); b += dpp_mov0<0x142>(b);   // row_bcast:15
    a += dpp_mov0<0x143>(a); b += dpp_mov0<0x143>(b);   // row_bcast:31
    a = __int_as_float(__builtin_amdgcn_readlane(__float_as_int(a), 63));
    b = __int_as_float(__builtin_amdgcn_readlane(__float_as_int(b), 63));
}

// DMA global->LDS, 16 B/lane (zero VGPR cost; decouples MLP from registers).
typedef const __attribute__((address_space(1))) unsigned int gas_u32;
typedef __attribute__((address_space(3))) unsigned int las_u32;
__device__ __forceinline__ void gload_lds16(const void* g, void* l) {
    __builtin_amdgcn_global_load_lds((gas_u32*)g, (las_u32*)l, 16, 0, 0);
}
#define VM_WAIT() asm volatile("s_waitcnt vmcnt(0)" ::: "memory")

// ---------------------------------------------------------------------------
// Pass 1: DMA-stage the chunk to LDS (12 x dwordx4, zero VGPRs), compute
// per-chunk affine aggregates (P,Q)[d] and scalar (pa,qa). Full fp32 --
// NO bf16 side-band, NO DT/ME writes. Epilogue: one float4 store.
// ---------------------------------------------------------------------------
__global__ __launch_bounds__(NTHR, 3) void pass1_kernel(
    const float* __restrict__ C, const float* __restrict__ V, const float* __restrict__ W,
    const float* __restrict__ enc, const float* __restrict__ tmod, const float* __restrict__ cmod,
    float2* __restrict__ PQ,      // [NWAVE*DD]: (P,Q) per (gc,d)
    float2* __restrict__ PaQa)    // [NWAVE]:    (pa,qa) per gc
{
    __shared__ float lds[WPB][3][TT * DD];          // 48 KB/block

    const int wv   = threadIdx.x >> 6;
    const int lane = threadIdx.x & 63;
    const int gc   = blockIdx.x * WPB + wv;        // global chunk id = b*NCH + ch
    const int b    = gc >> 9;                      // / NCH (512)
    const int ch   = gc & (NCH - 1);
    const int d2   = lane << 1;

    const int t0 = ch * TT;
    const size_t chunk = ((size_t)b * SS + t0) * DD;
    const char* Cc = (const char*)(C + chunk);
    const char* Wc = (const char*)(W + chunk);
    const char* Vc = (const char*)(V + chunk);

#pragma unroll
    for (int i = 0; i < 4; ++i) {
        const size_t bo = (size_t)i * 1024 + (size_t)lane * 16;
        gload_lds16(Cc + bo, &lds[wv][0][i * 256]);
        gload_lds16(Wc + bo, &lds[wv][1][i * 256]);
        gload_lds16(Vc + bo, &lds[wv][2][i * 256]);
    }

    const float2 tm = *(const float2*)(tmod + d2);
    const float2 cm = *(const float2*)(cmod + d2);
    const float2 ec = *(const float2*)(enc + b * DD + d2);

    VM_WAIT();

    float2 ctx;
    ctx.x = sigm(ec.x * cm.x) * ec.x;
    ctx.y = sigm(ec.y * cm.y) * ec.y;

    float2 P = make_float2(1.f, 1.f);
    float2 Q = make_float2(0.f, 0.f);
    float sdp[TT], sep[TT];

#pragma unroll
    for (int t = 0; t < TT; ++t) {
        const float2 cv = *(const float2*)&lds[wv][0][t * DD + d2];
        const float2 wl = *(const float2*)&lds[wv][1][t * DD + d2];
        const float2 vl = *(const float2*)&lds[wv][2][t * DD + d2];

        float2 dec, e2, T2;
        dec.x = sigm(wl.x * tm.x); dec.y = sigm(wl.y * tm.y);
        e2.x = __expf(cv.x); e2.y = __expf(cv.y);
        T2.x = e2.x * vl.x + ctx.x;
        T2.y = e2.y * vl.y + ctx.y;

        Q.x = dec.x * Q.x + T2.x;
        Q.y = dec.y * Q.y + T2.y;
        P.x *= dec.x; P.y *= dec.y;

        sdp[t] = dec.x + dec.y;
        sep[t] = e2.x + e2.y;
    }

    // batched reductions: TT independent trees -> full ILP
#pragma unroll
    for (int t = 0; t < TT; ++t) wave_red2(sdp[t], sep[t]);

    float pa = 1.f, qa = 0.f;
#pragma unroll
    for (int t = 0; t < TT; ++t) {
        const float mt = sdp[t] * (1.0f / DD);
        pa *= mt;
        qa = mt * qa + sep[t];
    }

    float4 pq4;
    pq4.x = P.x; pq4.y = Q.x; pq4.z = P.y; pq4.w = Q.y;
    *(float4*)(PQ + (size_t)gc * DD + d2) = pq4;   // coalesced 16B/lane
    if (lane == 0) PaQa[gc] = make_float2(pa, qa);
}

// ---------------------------------------------------------------------------
// Pass 2 (NEW): barrier-free wave-parallel scan. One wave per (b,d): each
// lane serially composes its 8 contiguous chunks, 6-round shfl_up affine
// scan across lanes, replay-write chunk entry states. 16 extra waves do the
// scalar a-scan the same way. No LDS, no __syncthreads, 516 blocks.
// ---------------------------------------------------------------------------
__global__ __launch_bounds__(256, 4) void pass2_kernel(
    const float2* __restrict__ PQ, const float2* __restrict__ PaQa,
    float* __restrict__ bst0,      // [NWAVE*DD] entry state per (gc,d)
    float* __restrict__ a0)        // [NWAVE]    entry a per gc
{
    const int wv   = threadIdx.x >> 6;
    const int lane = threadIdx.x & 63;
    const int wid  = blockIdx.x * 4 + wv;          // 0..2063

    if (wid < BB * DD) {
        // ---- (b,d)-wave: scan 512 chunk affines ----
        const int b = wid >> 7;
        const int d = wid & (DD - 1);
        const int ch0 = lane * 8;                  // 8 contiguous chunks/lane
        const size_t base = ((size_t)b * NCH + ch0) * DD + d;

        float2 A[8];
#pragma unroll
        for (int i = 0; i < 8; ++i) A[i] = PQ[base + (size_t)i * DD];

        // lane-serial composite (chunk order)
        float p = 1.f, q = 0.f;
#pragma unroll
        for (int i = 0; i < 8; ++i) { q = A[i].x * q + A[i].y; p = A[i].x * p; }

        // wave inclusive scan of affine pairs (identity-fill via lane guard)
#pragma unroll
        for (int dl = 1; dl < 64; dl <<= 1) {
            float ps = __shfl_up(p, dl);
            float qs = __shfl_up(q, dl);
            ps = (lane >= dl) ? ps : 1.f;
            qs = (lane >= dl) ? qs : 0.f;
            q = p * qs + q;        // compose: earlier segment applied first
            p = p * ps;
        }

        // exclusive entry value (init state 0) = inclusive[lane-1].q
        float x = __shfl_up(q, 1);
        x = (lane >= 1) ? x : 0.f;

        // replay: write entry per chunk
#pragma unroll
        for (int i = 0; i < 8; ++i) {
            bst0[base + (size_t)i * DD] = x;
            x = A[i].x * x + A[i].y;
        }
    } else if (wid < BB * DD + BB) {
        // ---- a-scan wave: one per batch ----
        const int b = wid - BB * DD;
        const int ch0 = lane * 8;

        float2 A[8];
#pragma unroll
        for (int i = 0; i < 8; ++i) A[i] = PaQa[b * NCH + ch0 + i];

        float p = 1.f, q = 0.f;
#pragma unroll
        for (int i = 0; i < 8; ++i) { q = A[i].x * q + A[i].y; p = A[i].x * p; }

#pragma unroll
        for (int dl = 1; dl < 64; dl <<= 1) {
            float ps = __shfl_up(p, dl);
            float qs = __shfl_up(q, dl);
            ps = (lane >= dl) ? ps : 1.f;
            qs = (lane >= dl) ? qs : 0.f;
            q = p * qs + q;
            p = p * ps;
        }

        float x = __shfl_up(q, 1);
        x = (lane >= 1) ? x : 0.f;
#pragma unroll
        for (int i = 0; i < 8; ++i) {
            a0[b * NCH + ch0 + i] = x;
            x = A[i].x * x + A[i].y;
        }
    }
}

// ---------------------------------------------------------------------------
// Pass 3: DMA-stage C,W,V again (L3-warm), RECOMPUTE dec/e/T (fp32, two LDS
// passes to cap registers), replay from entry state, fused LayerNorm.
// ---------------------------------------------------------------------------
__global__ __launch_bounds__(NTHR, 3) void pass3_kernel(
    const float* __restrict__ C, const float* __restrict__ V, const float* __restrict__ W,
    const float* __restrict__ enc, const float* __restrict__ tmod, const float* __restrict__ cmod,
    const float* __restrict__ lnw, const float* __restrict__ lnb,
    const float* __restrict__ bst0, const float* __restrict__ a0,
    float* __restrict__ out)
{
    __shared__ float lds[WPB][3][TT * DD];          // 48 KB/block

    const int wv   = threadIdx.x >> 6;
    const int lane = threadIdx.x & 63;
    const int gc   = blockIdx.x * WPB + wv;
    const int b    = gc >> 9;
    const int ch   = gc & (NCH - 1);
    const int d2   = lane << 1;

    const int t0 = ch * TT;
    const size_t chunk = ((size_t)b * SS + t0) * DD;
    const char* Cc = (const char*)(C + chunk);
    const char* Wc = (const char*)(W + chunk);
    const char* Vc = (const char*)(V + chunk);
    float2* Op = (float2*)(out + chunk + d2);

#pragma unroll
    for (int i = 0; i < 4; ++i) {
        const size_t bo = (size_t)i * 1024 + (size_t)lane * 16;
        gload_lds16(Cc + bo, &lds[wv][0][i * 256]);
        gload_lds16(Wc + bo, &lds[wv][1][i * 256]);
        gload_lds16(Vc + bo, &lds[wv][2][i * 256]);
    }

    const float2 tm = *(const float2*)(tmod + d2);
    const float2 cm = *(const float2*)(cmod + d2);
    const float2 ec = *(const float2*)(enc + b * DD + d2);
    const float2 gw = *(const float2*)(lnw + d2);
    const float2 gb = *(const float2*)(lnb + d2);
    float2 bst = *(const float2*)(bst0 + (size_t)gc * DD + d2);
    const float a_in = a0[gc];

    VM_WAIT();

    float2 ctx;
    ctx.x = sigm(ec.x * cm.x) * ec.x;
    ctx.y = sigm(ec.y * cm.y) * ec.y;

    // ---- LDS pass A: per-step mean partials only (keeps regs low) ----
    float sdp[TT], sep[TT];
#pragma unroll
    for (int t = 0; t < TT; ++t) {
        const float2 cv = *(const float2*)&lds[wv][0][t * DD + d2];
        const float2 wl = *(const float2*)&lds[wv][1][t * DD + d2];
        sdp[t] = sigm(wl.x * tm.x) + sigm(wl.y * tm.y);
        sep[t] = __expf(cv.x) + __expf(cv.y);
    }
#pragma unroll
    for (int t = 0; t < TT; ++t) wave_red2(sdp[t], sep[t]);

    // ---- LDS pass B: recompute dec/T, replay recurrence, build o[t] ----
    float a = a_in;
    float2 o[TT];
    float s1p[TT], s2p[TT];
#pragma unroll
    for (int t = 0; t < TT; ++t) {
        const float2 cv = *(const float2*)&lds[wv][0][t * DD + d2];
        const float2 wl = *(const float2*)&lds[wv][1][t * DD + d2];
        const float2 vl = *(const float2*)&lds[wv][2][t * DD + d2];

        float2 dec, e2, T2;
        dec.x = sigm(wl.x * tm.x); dec.y = sigm(wl.y * tm.y);
        e2.x = __expf(cv.x); e2.y = __expf(cv.y);
        T2.x = e2.x * vl.x + ctx.x;
        T2.y = e2.y * vl.y + ctx.y;

        const float mt = sdp[t] * (1.0f / DD);
        a = mt * a + sep[t];
        bst.x = dec.x * bst.x + T2.x;
        bst.y = dec.y * bst.y + T2.y;

        const float inva = fast_rcp(a + REC_EPS);
        o[t].x = bst.x * inva; o[t].y = bst.y * inva;
        s1p[t] = o[t].x + o[t].y;
        s2p[t] = o[t].x * o[t].x + o[t].y * o[t].y;
    }

#pragma unroll
    for (int t = 0; t < TT; ++t) wave_red2(s1p[t], s2p[t]);

#pragma unroll
    for (int t = 0; t < TT; ++t) {
        const float mu  = s1p[t] * (1.0f / DD);
        const float var = s2p[t] * (1.0f / DD) - mu * mu;
        const float rs  = rsqrtf(var + LN_EPS);
        float2 r;
        r.x = (o[t].x - mu) * rs * gw.x + gb.x;
        r.y = (o[t].y - mu) * rs * gw.y + gb.y;
        Op[t * (DD / 2)] = r;
    }
}

extern "C" void kernel_launch(void* const* d_in, const int* in_sizes, int n_in,
                              void* d_out, int out_size, void* d_ws, size_t ws_size,
                              hipStream_t stream)
{
    const float* C    = (const float*)d_in[0];
    const float* V    = (const float*)d_in[1];
    const float* W    = (const float*)d_in[2];
    const float* enc  = (const float*)d_in[3];
    const float* tmod = (const float*)d_in[4];
    const float* cmod = (const float*)d_in[5];
    const float* lnw  = (const float*)d_in[6];
    const float* lnb  = (const float*)d_in[7];
    float* out = (float*)d_out;

    // Workspace: ~12.7 MB total (no DT/ME side-bands anymore)
    float2* PQ   = (float2*)d_ws;                       // NWAVE*DD float2
    float2* PaQa = PQ + (size_t)NWAVE * DD;             // NWAVE float2
    float*  bst0 = (float*)(PaQa + NWAVE);              // NWAVE*DD floats
    float*  a0   = bst0 + (size_t)NWAVE * DD;           // NWAVE floats

    const int nblk = NWAVE / WPB;                       // 2048
    pass1_kernel<<<nblk, NTHR, 0, stream>>>(C, V, W, enc, tmod, cmod, PQ, PaQa);
    pass2_kernel<<<(BB * DD + BB) / 4, 256, 0, stream>>>(PQ, PaQa, bst0, a0);
    pass3_kernel<<<nblk, NTHR, 0, stream>>>(C, V, W, enc, tmod, cmod, lnw, lnb,
                                            bst0, a0, out);
}